// Round 1
// baseline (19451.340 us; speedup 1.0000x reference)
//
#include <hip/hip_runtime.h>

#define T_STEPS 512
#define BATCH   64
#define DIM     1024
#define HID     1024
#define G4      4096   // 4*HID

// ---------------------------------------------------------------------------
// Fused per-step LSTM kernel. One launch per timestep (512 graph nodes);
// kernel boundaries provide the h handoff (no cooperative launch, no
// grid.sync, no 512MB Xproj workspace — x@W_ih^T is fused into the step).
//
// gates[b][c] = sum_k x[b][k]*W_ih[n(c)][k]  (waves 0,1: K 0..1023)
//             + sum_k h[b][k]*W_hh[n(c)][k]  (waves 2,3: K 0..1023)
//   with n(c) = (c>>2)*HID + j0 + (c&3), c = gate*4 + jj.
//
// Block bid owns h-columns j0 = bid*4 .. j0+3 (16 gate columns, all 64 b).
// Each wave stages ITS OWN quarter of K into a wave-private LDS slice, so
// the chunk loop needs no __syncthreads at all. Global->reg prefetch of the
// next chunk overlaps the current chunk's FMAs. All LDS compute reads are
// float4 (h: 2-way bank alias = free; w: conflict-free broadcast).
// 4-way K-split partials reduced through LDS at the end (3 barriers/step).
// ---------------------------------------------------------------------------
__global__ __launch_bounds__(256) void lstm_step(
    const float* __restrict__ x,      // [B][DIM]   = inputs + t*B*DIM
    const float* __restrict__ hprev,  // [B][HID]   = h0 or out + (t-1)*B*HID
    const float* __restrict__ cprev,  // [B][HID]   = c0 or cbuf
    const float* __restrict__ Wih,    // [G4][DIM]
    const float* __restrict__ Whh,    // [G4][HID]
    const float* __restrict__ bih,    // [G4]
    const float* __restrict__ bhh,    // [G4]
    float* __restrict__ cnext,        // [B][HID]   = cbuf
    float* __restrict__ hout,         // [B][HID]   = out + t*B*HID
    float* __restrict__ tail)         // last step: hT [B][HID] ++ cT [B][HID]
{
    // wave-private staging: h_s[ks]/w_s[ks] touched only by wave ks.
    // strides 68/20 keep float4 reads 16B-aligned; h-read 2-way banks (free),
    // w-read conflict-free (4 addrs x 16-way broadcast).
    __shared__ float h_s[4][32][68];   // [ks][k][b]  34816 B
    __shared__ float w_s[4][32][20];   // [ks][k][c]  10240 B
    __shared__ float gates_s[64][17];  // [b][g*4+jj]  4352 B
    // partials alias h_s (used only after the post-loop barrier)
    float* part_s = &h_s[0][0][0];     // needs 256*17 = 4352 <= 8704 floats

    const int bid = blockIdx.x;        // 0..255
    const int tid = threadIdx.x;       // 0..255
    const int j0  = bid * 4;
    const int ks  = tid >> 6;          // wave id: 0,1 -> x half; 2,3 -> h half
    const int gl  = tid & 63;
    const int b0  = (gl >> 2) * 4;     // batch quad
    const int c0_ = (gl & 3) * 4;      // gate-col quad (gl&3 == gate id)

    const float* __restrict__ src = (ks < 2) ? x   : hprev;  // row stride 1024
    const float* __restrict__ W   = (ks < 2) ? Wih : Whh;    // row stride 1024
    const int kbase = (ks & 1) * 512;  // each wave owns 512 of its half's K

    float acc[4][4] = {};
    float4 hv[8], wv[2];

    // prefetch chunk 0 into registers
    {
        const int kb = kbase;
#pragma unroll
        for (int r = 0; r < 8; ++r) {
            const int fidx = r * 64 + gl;
            const int b    = fidx >> 3;            // 0..63
            const int k4   = (fidx & 7) * 4;       // 0..28
            hv[r] = *(const float4*)(src + b * DIM + kb + k4);
        }
#pragma unroll
        for (int r = 0; r < 2; ++r) {
            const int fidx = r * 64 + gl;
            const int c    = fidx >> 3;            // 0..15
            const int k4   = (fidx & 7) * 4;
            const int n    = (c >> 2) * HID + j0 + (c & 3);
            wv[r] = *(const float4*)(W + (size_t)n * DIM + kb + k4);
        }
    }

    for (int ci = 0; ci < 16; ++ci) {
        // regs -> LDS (wave-private slice; compiler orders vs own reads)
#pragma unroll
        for (int r = 0; r < 8; ++r) {
            const int fidx = r * 64 + gl;
            const int b    = fidx >> 3;
            const int k4   = (fidx & 7) * 4;
            h_s[ks][k4 + 0][b] = hv[r].x;
            h_s[ks][k4 + 1][b] = hv[r].y;
            h_s[ks][k4 + 2][b] = hv[r].z;
            h_s[ks][k4 + 3][b] = hv[r].w;
        }
#pragma unroll
        for (int r = 0; r < 2; ++r) {
            const int fidx = r * 64 + gl;
            const int c    = fidx >> 3;
            const int k4   = (fidx & 7) * 4;
            w_s[ks][k4 + 0][c] = wv[r].x;
            w_s[ks][k4 + 1][c] = wv[r].y;
            w_s[ks][k4 + 2][c] = wv[r].z;
            w_s[ks][k4 + 3][c] = wv[r].w;
        }
        // prefetch next chunk (loads fly under the FMAs below)
        if (ci < 15) {
            const int kb = kbase + (ci + 1) * 32;
#pragma unroll
            for (int r = 0; r < 8; ++r) {
                const int fidx = r * 64 + gl;
                const int b    = fidx >> 3;
                const int k4   = (fidx & 7) * 4;
                hv[r] = *(const float4*)(src + b * DIM + kb + k4);
            }
#pragma unroll
            for (int r = 0; r < 2; ++r) {
                const int fidx = r * 64 + gl;
                const int c    = fidx >> 3;
                const int k4   = (fidx & 7) * 4;
                const int n    = (c >> 2) * HID + j0 + (c & 3);
                wv[r] = *(const float4*)(W + (size_t)n * DIM + kb + k4);
            }
        }
        // compute: 4b x 4c per thread over 32 k, float4 LDS reads
#pragma unroll 16
        for (int kk = 0; kk < 32; ++kk) {
            const float4 h4 = *(const float4*)&h_s[ks][kk][b0];
            const float4 w4 = *(const float4*)&w_s[ks][kk][c0_];
            const float hr[4] = {h4.x, h4.y, h4.z, h4.w};
            const float wr[4] = {w4.x, w4.y, w4.z, w4.w};
#pragma unroll
            for (int i = 0; i < 4; ++i)
#pragma unroll
                for (int j = 0; j < 4; ++j)
                    acc[i][j] += hr[i] * wr[j];
        }
    }

    // --- reduce the 4 K-split partials (part_s aliases h_s: barrier first) ---
    __syncthreads();
#pragma unroll
    for (int i = 0; i < 4; ++i)
#pragma unroll
        for (int j = 0; j < 4; ++j)
            part_s[tid * 17 + i * 4 + j] = acc[i][j];
    __syncthreads();
    if (ks == 0) {
#pragma unroll
        for (int i = 0; i < 4; ++i)
#pragma unroll
            for (int j = 0; j < 4; ++j) {
                const int idx = i * 4 + j;
                const float s = part_s[gl * 17 + idx] +
                                part_s[(gl + 64) * 17 + idx] +
                                part_s[(gl + 128) * 17 + idx] +
                                part_s[(gl + 192) * 17 + idx];
                gates_s[b0 + i][c0_ + j] = s;
            }
    }
    __syncthreads();

    // --- elementwise LSTM cell update: thread -> (b, jj) ---
    {
        const int b  = tid >> 2;
        const int jj = tid & 3;
        const int j  = j0 + jj;
        const float pre_i = gates_s[b][0  + jj] + bih[0 * HID + j] + bhh[0 * HID + j];
        const float pre_f = gates_s[b][4  + jj] + bih[1 * HID + j] + bhh[1 * HID + j];
        const float pre_g = gates_s[b][8  + jj] + bih[2 * HID + j] + bhh[2 * HID + j];
        const float pre_o = gates_s[b][12 + jj] + bih[3 * HID + j] + bhh[3 * HID + j];
        const float ig = 1.0f / (1.0f + __expf(-pre_i));
        const float fg = 1.0f / (1.0f + __expf(-pre_f));
        const float gg = tanhf(pre_g);
        const float og = 1.0f / (1.0f + __expf(-pre_o));
        const float cp = cprev[b * HID + j];
        const float cn = fg * cp + ig * gg;
        const float hn = og * tanhf(cn);
        cnext[b * HID + j] = cn;
        hout[b * HID + j]  = hn;
        if (tail) {
            tail[b * HID + j] = hn;                              // h_T
            tail[(size_t)BATCH * HID + b * HID + j] = cn;        // c_T
        }
    }
}

// ---------------------------------------------------------------------------
extern "C" void kernel_launch(void* const* d_in, const int* in_sizes, int n_in,
                              void* d_out, int out_size, void* d_ws, size_t ws_size,
                              hipStream_t stream) {
    const float* inputs = (const float*)d_in[0];  // [T][B][DIM]
    const float* h0     = (const float*)d_in[1];  // [B][HID]
    const float* c0     = (const float*)d_in[2];  // [B][HID]
    const float* W_ih   = (const float*)d_in[3];  // [G4][DIM]
    const float* W_hh   = (const float*)d_in[4];  // [G4][HID]
    const float* b_ih   = (const float*)d_in[5];  // [G4]
    const float* b_hh   = (const float*)d_in[6];  // [G4]
    float* out  = (float*)d_out;

    // workspace: only the cell state (B*HID floats = 256 KB)
    float* cbuf = (float*)d_ws;

    for (int t = 0; t < T_STEPS; ++t) {
        const float* x  = inputs + (size_t)t * BATCH * DIM;
        const float* hp = (t == 0) ? h0 : out + (size_t)(t - 1) * BATCH * HID;
        const float* cp = (t == 0) ? c0 : cbuf;
        float* ho   = out + (size_t)t * BATCH * HID;
        float* tail = (t == T_STEPS - 1) ? out + (size_t)T_STEPS * BATCH * HID
                                         : nullptr;
        hipLaunchKernelGGL(lstm_step, dim3(256), dim3(256), 0, stream,
                           x, hp, cp, W_ih, W_hh, b_ih, b_hh, cbuf, ho, tail);
    }
}

// Round 2
// 11514.539 us; speedup vs baseline: 1.6893x; 1.6893x over previous
//
#include <hip/hip_runtime.h>

#define T_STEPS 512
#define BATCH   64
#define DIM     1024
#define HID     1024
#define G4      4096   // 4*HID

// ---------------------------------------------------------------------------
// Fused per-step LSTM kernel, v2: 512 threads (8 waves = 2/SIMD) per block.
// One launch per timestep (512 graph nodes); kernel boundaries provide the
// h handoff (no cooperative launch, no Xproj workspace).
//
// gates[b][c] = sum_k x[b][k]*W_ih[n(c)][k]  (waves 0..3, K 0..1023)
//             + sum_k h[b][k]*W_hh[n(c)][k]  (waves 4..7, K 0..1023)
//   with n(c) = (c>>2)*HID + j0 + (c&3), c = gate*4 + jj.
//
// Block bid owns h-columns j0 = bid*4 .. j0+3 (16 gate columns, all 64 b).
// Each wave stages ITS OWN 256-wide K-slice into a wave-private LDS slice
// (16 chunks x 16 k), so the chunk loop needs no __syncthreads at all —
// DS ops from one wave execute in order. Global->reg prefetch of the next
// chunk overlaps the FMA block; 2 waves/SIMD hide the remaining latency.
// All LDS compute reads are float4 (h: broadcast x4 + 2-way banks; w:
// broadcast x16, conflict-free). 8-way K-split partials reduced through
// LDS at the end (3 barriers/step total).
// ---------------------------------------------------------------------------
__global__ __launch_bounds__(512) void lstm_step(
    const float* __restrict__ x,      // [B][DIM]   = inputs + t*B*DIM
    const float* __restrict__ hprev,  // [B][HID]   = h0 or out + (t-1)*B*HID
    const float* __restrict__ cprev,  // [B][HID]   = c0 or cbuf
    const float* __restrict__ Wih,    // [G4][DIM]
    const float* __restrict__ Whh,    // [G4][HID]
    const float* __restrict__ bih,    // [G4]
    const float* __restrict__ bhh,    // [G4]
    float* __restrict__ cnext,        // [B][HID]   = cbuf
    float* __restrict__ hout,         // [B][HID]   = out + t*B*HID
    float* __restrict__ tail)         // last step: hT [B][HID] ++ cT [B][HID]
{
    // wave-private staging slices; strides 68/20 keep float4 reads
    // 16B-aligned and writes <=2-way banked.
    __shared__ float h_s[8][16][68];   // [wv][k][b]  34816 B
    __shared__ float w_s[8][16][20];   // [wv][k][c]  10240 B
    __shared__ float gates_s[64][17];  // [b][g*4+jj]  4352 B
    // partials alias h_s (used only after the post-loop barrier);
    // needs 512*17 = 8704 floats; h_s holds 8*16*68 = 8704. exact fit.
    float* part_s = &h_s[0][0][0];

    const int bid = blockIdx.x;        // 0..255
    const int tid = threadIdx.x;       // 0..511
    const int j0  = bid * 4;
    const int wv  = tid >> 6;          // wave id 0..7
    const int gl  = tid & 63;
    const int b0  = (gl >> 2) * 4;     // batch quad
    const int c0_ = (gl & 3) * 4;      // gate-col quad (gl&3 == gate id)

    const float* __restrict__ src = (wv < 4) ? x   : hprev;  // row stride 1024
    const float* __restrict__ W   = (wv < 4) ? Wih : Whh;    // row stride 1024
    const int kbase = (wv & 3) * 256;  // this wave's K-slice

    float acc[4][4] = {};
    float4 hv[4], wvf;

    // prefetch chunk 0 into registers
    {
        const int kb = kbase;
#pragma unroll
        for (int r = 0; r < 4; ++r) {
            const int fidx = r * 64 + gl;          // 0..255
            const int b    = fidx >> 2;            // 0..63
            const int k4   = (fidx & 3) * 4;       // 0,4,8,12
            hv[r] = *(const float4*)(src + b * DIM + kb + k4);
        }
        {
            const int c  = gl >> 2;                // 0..15
            const int k4 = (gl & 3) * 4;
            const int n  = (c >> 2) * HID + j0 + (c & 3);
            wvf = *(const float4*)(W + (size_t)n * DIM + kb + k4);
        }
    }

    for (int ci = 0; ci < 16; ++ci) {
        // regs -> LDS (wave-private slice; same-wave DS ops are in-order)
#pragma unroll
        for (int r = 0; r < 4; ++r) {
            const int fidx = r * 64 + gl;
            const int b    = fidx >> 2;
            const int k4   = (fidx & 3) * 4;
            h_s[wv][k4 + 0][b] = hv[r].x;
            h_s[wv][k4 + 1][b] = hv[r].y;
            h_s[wv][k4 + 2][b] = hv[r].z;
            h_s[wv][k4 + 3][b] = hv[r].w;
        }
        {
            const int c  = gl >> 2;
            const int k4 = (gl & 3) * 4;
            w_s[wv][k4 + 0][c] = wvf.x;
            w_s[wv][k4 + 1][c] = wvf.y;
            w_s[wv][k4 + 2][c] = wvf.z;
            w_s[wv][k4 + 3][c] = wvf.w;
        }
        // prefetch next chunk (loads fly under the FMAs below)
        if (ci < 15) {
            const int kb = kbase + (ci + 1) * 16;
#pragma unroll
            for (int r = 0; r < 4; ++r) {
                const int fidx = r * 64 + gl;
                const int b    = fidx >> 2;
                const int k4   = (fidx & 3) * 4;
                hv[r] = *(const float4*)(src + b * DIM + kb + k4);
            }
            {
                const int c  = gl >> 2;
                const int k4 = (gl & 3) * 4;
                const int n  = (c >> 2) * HID + j0 + (c & 3);
                wvf = *(const float4*)(W + (size_t)n * DIM + kb + k4);
            }
        }
        // compute: 4b x 4c per thread over 16 k, float4 LDS reads
#pragma unroll
        for (int kk = 0; kk < 16; ++kk) {
            const float4 h4 = *(const float4*)&h_s[wv][kk][b0];
            const float4 w4 = *(const float4*)&w_s[wv][kk][c0_];
            const float hr[4] = {h4.x, h4.y, h4.z, h4.w};
            const float wr[4] = {w4.x, w4.y, w4.z, w4.w};
#pragma unroll
            for (int i = 0; i < 4; ++i)
#pragma unroll
                for (int j = 0; j < 4; ++j)
                    acc[i][j] += hr[i] * wr[j];
        }
    }

    // --- reduce the 8 K-split partials (part_s aliases h_s: barrier first) ---
    __syncthreads();
#pragma unroll
    for (int i = 0; i < 4; ++i)
#pragma unroll
        for (int j = 0; j < 4; ++j)
            part_s[tid * 17 + i * 4 + j] = acc[i][j];
    __syncthreads();
    if (tid < 64) {
#pragma unroll
        for (int i = 0; i < 4; ++i)
#pragma unroll
            for (int j = 0; j < 4; ++j) {
                const int idx = i * 4 + j;
                float s = 0.0f;
#pragma unroll
                for (int p = 0; p < 8; ++p)
                    s += part_s[(gl + 64 * p) * 17 + idx];
                gates_s[b0 + i][c0_ + j] = s;
            }
    }
    __syncthreads();

    // --- elementwise LSTM cell update: thread -> (b, jj), waves 0..3 ---
    if (tid < 256) {
        const int b  = tid >> 2;
        const int jj = tid & 3;
        const int j  = j0 + jj;
        const float pre_i = gates_s[b][0  + jj] + bih[0 * HID + j] + bhh[0 * HID + j];
        const float pre_f = gates_s[b][4  + jj] + bih[1 * HID + j] + bhh[1 * HID + j];
        const float pre_g = gates_s[b][8  + jj] + bih[2 * HID + j] + bhh[2 * HID + j];
        const float pre_o = gates_s[b][12 + jj] + bih[3 * HID + j] + bhh[3 * HID + j];
        const float ig = 1.0f / (1.0f + __expf(-pre_i));
        const float fg = 1.0f / (1.0f + __expf(-pre_f));
        const float gg = tanhf(pre_g);
        const float og = 1.0f / (1.0f + __expf(-pre_o));
        const float cp = cprev[b * HID + j];
        const float cn = fg * cp + ig * gg;
        const float hn = og * tanhf(cn);
        cnext[b * HID + j] = cn;
        hout[b * HID + j]  = hn;
        if (tail) {
            tail[b * HID + j] = hn;                              // h_T
            tail[(size_t)BATCH * HID + b * HID + j] = cn;        // c_T
        }
    }
}

// ---------------------------------------------------------------------------
extern "C" void kernel_launch(void* const* d_in, const int* in_sizes, int n_in,
                              void* d_out, int out_size, void* d_ws, size_t ws_size,
                              hipStream_t stream) {
    const float* inputs = (const float*)d_in[0];  // [T][B][DIM]
    const float* h0     = (const float*)d_in[1];  // [B][HID]
    const float* c0     = (const float*)d_in[2];  // [B][HID]
    const float* W_ih   = (const float*)d_in[3];  // [G4][DIM]
    const float* W_hh   = (const float*)d_in[4];  // [G4][HID]
    const float* b_ih   = (const float*)d_in[5];  // [G4]
    const float* b_hh   = (const float*)d_in[6];  // [G4]
    float* out  = (float*)d_out;

    // workspace: only the cell state (B*HID floats = 256 KB)
    float* cbuf = (float*)d_ws;

    for (int t = 0; t < T_STEPS; ++t) {
        const float* x  = inputs + (size_t)t * BATCH * DIM;
        const float* hp = (t == 0) ? h0 : out + (size_t)(t - 1) * BATCH * HID;
        const float* cp = (t == 0) ? c0 : cbuf;
        float* ho   = out + (size_t)t * BATCH * HID;
        float* tail = (t == T_STEPS - 1) ? out + (size_t)T_STEPS * BATCH * HID
                                         : nullptr;
        hipLaunchKernelGGL(lstm_step, dim3(256), dim3(512), 0, stream,
                           x, hp, cp, W_ih, W_hh, b_ih, b_hh, cbuf, ho, tail);
    }
}